// Round 7
// baseline (515.522 us; speedup 1.0000x reference)
//
#include <hip/hip_runtime.h>
#include <hip/hip_bf16.h>

// ActLayer: out[b,o] = sum_{i,f} norm(sin(w_f x[b,i] + p_f)) * beta[f,o] * lamb[i,o] + bias[o]
//
// Round-7 = Round-6 with the LDS overflow fixed (betaR table bf16, 16 KB;
// total static LDS 46.6 KB < 64 KiB — round 6 was 72 KB and NEVER LAUNCHED).
//   - Round-2's verified synchronization: cooperative A staging each f,
//     single buffer, stage -> barrier -> consume -> barrier.
//   - Wave grid 4x1: wave w consumes A rows w*16..w*16+15, all 128 cols.
//   - Lambda bf16 fragments staged to LDS once per i-tile, held in 64 VGPRs
//     (lf[2][8]) across the f-loop -> NO per-f B staging.
//   - betaR bf16 LDS table [f][c=o%16][nt=o/16]; per f: 2x 8B reads + cvt.
//   - Fold per f: oacc[nt] += br[nt] * S_f.
//
// B=8192, I=512, F=64, O=512. BM=64, BN=128. Grid 512 blocks.

#define TB 256

typedef __attribute__((ext_vector_type(8))) short short8;
typedef __attribute__((ext_vector_type(4))) float floatx4;
typedef __attribute__((ext_vector_type(4))) unsigned int uintx4;
typedef __attribute__((ext_vector_type(4))) unsigned short ushort4t;

__device__ __forceinline__ unsigned pk_bf16(float a, float b) {
    __hip_bfloat162 h = __float22bfloat162_rn(make_float2(a, b));
    union { __hip_bfloat162 h2; unsigned u; } cv; cv.h2 = h; return cv.u;
}
__device__ __forceinline__ unsigned short f_to_bf16u(float v) {
    union { __hip_bfloat16 h; unsigned short u; } cv;
    cv.h = __float2bfloat16(v);
    return cv.u;
}
__device__ __forceinline__ float bf16u_to_f(unsigned short v) {
    union { unsigned u; float f; } cv; cv.u = ((unsigned)v) << 16; return cv.f;
}

__global__ __launch_bounds__(TB, 2)
void actlayer_kernel(const float* __restrict__ x,
                     const float* __restrict__ freqs,
                     const float* __restrict__ phases,
                     const float* __restrict__ beta,
                     const float* __restrict__ lamb,
                     const float* __restrict__ bias,
                     float* __restrict__ out)
{
    constexpr int I = 512, F = 64, O = 512;
    constexpr int BN = 128;
    const int t  = threadIdx.x;
    const int bx = blockIdx.x;
    const int bn = bx & 3;            // 0..3
    const int bm = bx >> 2;           // 0..127
    const int n0 = bn * BN;
    const int m0 = bm * 64;

    __shared__ __align__(16) unsigned short A_sh[64][72];    // sin tile [m][k]   (9.2 KB)
    __shared__ __align__(16) unsigned short L_sh[BN][72];    // lambda bf16 [n][k] (18.4 KB)
    __shared__ __align__(16) unsigned short brP_sh[F][16][8];// betaR bf16 [f][c][nt] (16 KB)
    __shared__ float wrev_sh[F], prev_sh[F], r_sh[F], m_sh[F];
    __shared__ float c_sh[BN];
    __shared__ float slp_sh[2][BN];
    // total static LDS = 46.6 KB  (< 64 KiB per-block limit!)

    // ---- prologue: per-f normalization constants ----
    if (t < F) {
        float wq = freqs[t];
        float ph = phases[t];
        float e1 = expf(-0.5f * wq * wq);
        float mean = e1 * sinf(ph);
        float e2 = expf(-2.0f * wq * wq);
        float var = 0.5f - 0.5f * e2 * cosf(2.0f * ph) - mean * mean;
        float r = 1.0f / sqrtf(1e-3f + var);
        wrev_sh[t] = wq * 0.15915494309189535f;   // /2pi -> revolutions for v_sin
        prev_sh[t] = ph * 0.15915494309189535f;
        r_sh[t] = r;
        m_sh[t] = mean;
    }
    // sl[n] = sum_i lamb[i][n0+n], split over 2 halves of i
    {
        int n = t & 127, half = t >> 7;
        float s = 0.f;
        const float* lp = lamb + (size_t)(half * 256) * O + n0 + n;
        #pragma unroll 8
        for (int i = 0; i < 256; ++i) s += lp[(size_t)i * O];
        slp_sh[half][n] = s;
    }
    __syncthreads();
    // brP[f][c][nt] = beta[f][n0 + nt*16 + c] * r_f   (bf16)
    #pragma unroll
    for (int j = 0; j < 32; ++j) {
        int e = t + TB * j;          // 0..8191
        int f = e >> 7;              // 0..63
        int rem = e & 127;           // = nt*16 + c
        int nt = rem >> 4;
        int c  = rem & 15;
        brP_sh[f][c][nt] = f_to_bf16u(beta[f * O + n0 + rem] * r_sh[f]);
    }
    __syncthreads();
    if (t < BN) {
        int c = t & 15, nt = t >> 4;
        float sb = 0.f;
        #pragma unroll
        for (int f = 0; f < F; ++f) sb += bf16u_to_f(brP_sh[f][c][nt]) * m_sh[f];
        c_sh[t] = bias[n0 + t] - sb * (slp_sh[0][t] + slp_sh[1][t]);
    }
    // (c_sh visibility to epilogue guaranteed by in-loop barriers)

    // ---- staging geometry (round-2 verbatim): runs of 8 consecutive k ----
    const int kr = t & 7;          // k-run: k = kr*8 .. +8
    const int r0 = t >> 3;         // 0..31

    // ---- wave geometry: 4x1 grid, wave w consumes rows w*16.. ----
    const int lane = t & 63;
    const int w    = t >> 6;       // 0..3
    const int l15  = lane & 15;
    const int quad = lane >> 4;

    floatx4 oacc[8];
    #pragma unroll
    for (int b = 0; b < 8; ++b) oacc[b] = (floatx4){0.f, 0.f, 0.f, 0.f};

    const floatx4 zero4 = (floatx4){0.f, 0.f, 0.f, 0.f};

    #pragma unroll 1
    for (int it = 0; it < 8; ++it) {
        const int i0 = it * 64;
        __syncthreads();   // protect L_sh from previous i-tile's fragment reads
        // stage lambda tile -> LDS (bf16): thread = one column, 32 k values
        {
            int n  = t & 127;
            int kh = t >> 7;           // 0..1
            const float* lp = lamb + (size_t)(i0 + kh * 32) * O + n0 + n;
            float v[32];
            #pragma unroll
            for (int k = 0; k < 32; ++k) v[k] = lp[(size_t)k * O];
            #pragma unroll
            for (int rr = 0; rr < 4; ++rr) {
                uintx4 w4;
                w4.x = pk_bf16(v[rr*8+0], v[rr*8+1]);
                w4.y = pk_bf16(v[rr*8+2], v[rr*8+3]);
                w4.z = pk_bf16(v[rr*8+4], v[rr*8+5]);
                w4.w = pk_bf16(v[rr*8+6], v[rr*8+7]);
                *(uintx4*)&L_sh[n][kh * 32 + rr * 8] = w4;
            }
        }
        // x values for A staging (round-2 verbatim): rows r0, r0+32, k=kr*8..+7
        float xr[2][8];
        #pragma unroll
        for (int j = 0; j < 2; ++j) {
            int m = r0 + 32 * j;
            const float* xp = x + (size_t)(m0 + m) * I + i0 + kr * 8;
            float4 v0 = *(const float4*)(xp);
            float4 v1 = *(const float4*)(xp + 4);
            xr[j][0]=v0.x; xr[j][1]=v0.y; xr[j][2]=v0.z; xr[j][3]=v0.w;
            xr[j][4]=v1.x; xr[j][5]=v1.y; xr[j][6]=v1.z; xr[j][7]=v1.w;
        }
        __syncthreads();
        // lambda fragments for all 8 n-tiles x 2 k-chunks (held across f-loop)
        short8 lf[2][8];
        #pragma unroll
        for (int kk = 0; kk < 2; ++kk)
            #pragma unroll
            for (int nt = 0; nt < 8; ++nt) {
                uintx4 lv = *(const uintx4*)&L_sh[nt * 16 + l15][kk * 32 + quad * 8];
                lf[kk][nt] = __builtin_bit_cast(short8, lv);
            }

        #pragma unroll 1
        for (int f = 0; f < F; ++f) {
            float wfr = wrev_sh[f], pfr = prev_sh[f];
            // stage A: sin(w_f * x + p_f) -> bf16 (round-2 verbatim pattern)
            #pragma unroll
            for (int j = 0; j < 2; ++j) {
                int m = r0 + 32 * j;
                float s[8];
                #pragma unroll
                for (int jj = 0; jj < 8; ++jj) {
                    float arg = __builtin_amdgcn_fractf(fmaf(xr[j][jj], wfr, pfr));
                    s[jj] = __builtin_amdgcn_sinf(arg);
                }
                uintx4 w4;
                w4.x = pk_bf16(s[0], s[1]); w4.y = pk_bf16(s[2], s[3]);
                w4.z = pk_bf16(s[4], s[5]); w4.w = pk_bf16(s[6], s[7]);
                *(uintx4*)&A_sh[m][kr * 8] = w4;
            }
            __syncthreads();
            // A fragments for this wave's 16 rows
            uintx4 a0v = *(const uintx4*)&A_sh[w * 16 + l15][quad * 8];
            uintx4 a1v = *(const uintx4*)&A_sh[w * 16 + l15][32 + quad * 8];
            short8 af0 = __builtin_bit_cast(short8, a0v);
            short8 af1 = __builtin_bit_cast(short8, a1v);
            // betaR for this f: 8 bf16 via 2x 8-byte LDS reads
            ushort4t bru0 = *(const ushort4t*)&brP_sh[f][l15][0];
            ushort4t bru1 = *(const ushort4t*)&brP_sh[f][l15][4];
            float br[8];
            #pragma unroll
            for (int nt = 0; nt < 4; ++nt) {
                br[nt]     = bf16u_to_f(bru0[nt]);
                br[nt + 4] = bf16u_to_f(bru1[nt]);
            }
            // S_f = A_f @ Lambda ; oacc += betaR (.) S_f
            #pragma unroll
            for (int nt = 0; nt < 8; ++nt) {
                floatx4 sacc = __builtin_amdgcn_mfma_f32_16x16x32_bf16(
                    af0, lf[0][nt], zero4, 0, 0, 0);
                sacc = __builtin_amdgcn_mfma_f32_16x16x32_bf16(
                    af1, lf[1][nt], sacc, 0, 0, 0);
                oacc[nt] += br[nt] * sacc;
            }
            __syncthreads();
        }
    }

    // ---- epilogue: add per-column constant, store fp32 ----
    const int gm = m0 + w * 16 + quad * 4;
    #pragma unroll
    for (int nt = 0; nt < 8; ++nt) {
        int gn = n0 + nt * 16 + l15;
        float cv = c_sh[nt * 16 + l15];
        #pragma unroll
        for (int rg = 0; rg < 4; ++rg) {
            out[(size_t)(gm + rg) * O + gn] = oacc[nt][rg] + cv;
        }
    }
}

extern "C" void kernel_launch(void* const* d_in, const int* in_sizes, int n_in,
                              void* d_out, int out_size, void* d_ws, size_t ws_size,
                              hipStream_t stream) {
    const float* x      = (const float*)d_in[0];
    const float* freqs  = (const float*)d_in[1];
    const float* phases = (const float*)d_in[2];
    const float* beta   = (const float*)d_in[3];
    const float* lamb   = (const float*)d_in[4];
    const float* bias   = (const float*)d_in[5];
    float* out = (float*)d_out;

    dim3 grid(512);   // (8192/64) m-blocks * (512/128) n-blocks
    dim3 block(TB);
    hipLaunchKernelGGL(actlayer_kernel, grid, block, 0, stream,
                       x, freqs, phases, beta, lamb, bias, out);
}